// Round 4
// baseline (434.862 us; speedup 1.0000x reference)
//
#include <hip/hip_runtime.h>
#include <hip/hip_bf16.h>
#include <stdint.h>

#define D_IN  4096
#define D_OUT 4096
#define MROWS 8192   // 2 * 4096 rows of x

using i32x4  = __attribute__((ext_vector_type(4))) int;
using i32x16 = __attribute__((ext_vector_type(16))) int;

// -------- Kernel 1 (fused): RMSNorm -> i8 xn (per-row absmax scale)
//          AND w_q fp32 -> i8 (exact, values in {-1,0,1}) ------------------
__global__ __launch_bounds__(256) void prep_kernel(
    const float* __restrict__ x, const float* __restrict__ nw,
    signed char* __restrict__ xq, float* __restrict__ srow,
    const float* __restrict__ wq, signed char* __restrict__ wb) {
  const int b = blockIdx.x;
  const int t = threadIdx.x;

  if (b < MROWS) {
    const float4* xr  = (const float4*)(x + (size_t)b * D_IN);
    const float4* nw4 = (const float4*)nw;

    float4 p[4];
    float ss = 0.f, mx = 0.f;
#pragma unroll
    for (int i = 0; i < 4; ++i) {
      const float4 v = xr[i * 256 + t];
      const float4 w = nw4[i * 256 + t];
      ss += v.x * v.x + v.y * v.y + v.z * v.z + v.w * v.w;
      p[i].x = v.x * w.x; p[i].y = v.y * w.y;
      p[i].z = v.z * w.z; p[i].w = v.w * w.w;
      mx = fmaxf(mx, fmaxf(fmaxf(fabsf(p[i].x), fabsf(p[i].y)),
                           fmaxf(fabsf(p[i].z), fabsf(p[i].w))));
    }
#pragma unroll
    for (int off = 32; off > 0; off >>= 1) {
      ss += __shfl_down(ss, off, 64);
      mx = fmaxf(mx, __shfl_down(mx, off, 64));
    }

    __shared__ float rs[4], rm[4];
    if ((t & 63) == 0) { rs[t >> 6] = ss; rm[t >> 6] = mx; }
    __syncthreads();
    const float scale =
        rsqrtf((rs[0] + rs[1] + rs[2] + rs[3]) * (1.0f / D_IN) + 1e-6f);
    const float rowmax = fmaxf(fmaxf(rm[0], rm[1]), fmaxf(rm[2], rm[3])) * scale;
    const float s   = fmaxf(rowmax, 1e-20f) * (1.0f / 127.0f);
    const float f   = scale / s;   // = scale * 127 / rowmax
    if (t == 0) srow[b] = s;

    int* out = (int*)(xq + (size_t)b * D_IN);
#pragma unroll
    for (int i = 0; i < 4; ++i) {
      const int q0 = (int)rintf(p[i].x * f);
      const int q1 = (int)rintf(p[i].y * f);
      const int q2 = (int)rintf(p[i].z * f);
      const int q3 = (int)rintf(p[i].w * f);
      out[i * 256 + t] =
          (q0 & 0xFF) | ((q1 & 0xFF) << 8) | ((q2 & 0xFF) << 16) | (q3 << 24);
    }
  } else {
    const int cb = b - MROWS;
    const float4* w4 = (const float4*)wq;
    int* o = (int*)wb;
#pragma unroll
    for (int i = 0; i < 4; ++i) {
      const int idx = cb * 1024 + i * 256 + t;
      const float4 v = w4[idx];
      const int q0 = (int)v.x, q1 = (int)v.y, q2 = (int)v.z, q3 = (int)v.w;
      o[idx] = (q0 & 0xFF) | ((q1 & 0xFF) << 8) | ((q2 & 0xFF) << 16) | (q3 << 24);
    }
  }
}

// ---------------- Kernel 2: i8 GEMM, 32x32x32 MFMA --------------------------
// A: MxK, B: NxK (B^T). Per 256-thread block: 128x128 tile, 2x2 wave grid,
// each wave 64x64 as 2x2 of 32x32 MFMAs, K-tile = 64 bytes (2 k-steps).
// Operand layout mfma_i32_32x32x32_i8: [m|n = lane&31][k = (lane>>5)*16 + j].
// C/D: col = lane&31, row = (reg&3) + 8*(reg>>2) + 4*(lane>>5)  [m74/m101].
// LDS XOR swizzle (0 conflicts, verified R2): 16B chunk (row, j) at slot
// j ^ ((row>>1)&3), applied on the global-source side of global_load_lds.
#define BM 128
#define BN 128
#define BKB 64   // K per tile, i8 elements == bytes

__global__ __launch_bounds__(256) void gemm_kernel(
    const signed char* __restrict__ A,   // MROWS x D_IN i8
    const signed char* __restrict__ B,   // D_OUT x D_IN i8
    const float* __restrict__ srow,      // MROWS   (per-row dequant scale)
    const float* __restrict__ gamma,     // D_OUT
    float* __restrict__ C) {             // MROWS x D_OUT fp32
  __shared__ __align__(16) signed char sA[BM * BKB];  // 8 KB
  __shared__ __align__(16) signed char sB[BN * BKB];  // 8 KB

  const int tid  = threadIdx.x;
  const int lane = tid & 63;
  const int wv   = tid >> 6;
  const int wm   = wv & 1;        // 2x2 wave grid, each wave owns 64x64
  const int wn   = wv >> 1;
  const int bn   = blockIdx.x;
  const int bm   = blockIdx.y;

  i32x16 acc[2][2];
#pragma unroll
  for (int i = 0; i < 2; ++i)
#pragma unroll
    for (int j = 0; j < 2; ++j)
#pragma unroll
      for (int r = 0; r < 16; ++r) acc[i][j][r] = 0;

  const size_t aBase = (size_t)(bm * BM) * D_IN;
  const size_t bBase = (size_t)(bn * BN) * D_IN;

  // staging: chunk c = i*256+tid -> tile row r=c>>2, slot c&3 holds global
  // chunk j = (c&3) ^ ((r>>1)&3)
  int r_[2], cc_[2];
#pragma unroll
  for (int i = 0; i < 2; ++i) {
    const int c = i * 256 + tid;
    r_[i]  = c >> 2;
    cc_[i] = ((c & 3) ^ ((r_[i] >> 1) & 3)) * 16;
  }

  // ds_read addresses (row base is multiple of 32, so (row>>1)&3 ==
  // ((lane&31)>>1)&3): tile i row = wm*64 + i*32 + (lane&31),
  // k-step ks chunk j = ks*2 + (lane>>5), slot = j ^ ((lane>>1)&3)
  const int mrow = lane & 31;
  const int sw   = (lane >> 1) & 3;
  const int jhi  = lane >> 5;

  for (int k0 = 0; k0 < D_IN; k0 += BKB) {
#pragma unroll
    for (int i = 0; i < 2; ++i) {
      __builtin_amdgcn_global_load_lds(
          (__attribute__((address_space(1))) void*)(A + aBase + (size_t)r_[i] * D_IN + k0 + cc_[i]),
          (__attribute__((address_space(3))) void*)&sA[(i * 256 + wv * 64) * 16],
          16, 0, 0);
    }
#pragma unroll
    for (int i = 0; i < 2; ++i) {
      __builtin_amdgcn_global_load_lds(
          (__attribute__((address_space(1))) void*)(B + bBase + (size_t)r_[i] * D_IN + k0 + cc_[i]),
          (__attribute__((address_space(3))) void*)&sB[(i * 256 + wv * 64) * 16],
          16, 0, 0);
    }
    __syncthreads();

    i32x4 af[2][2], bfr[2][2];   // [ks][tile]
#pragma unroll
    for (int ks = 0; ks < 2; ++ks) {
      const int slot = ((ks * 2 + jhi) ^ sw) * 16;
#pragma unroll
      for (int i = 0; i < 2; ++i) {
        af[ks][i]  = *(const i32x4*)&sA[(wm * 64 + i * 32 + mrow) * BKB + slot];
        bfr[ks][i] = *(const i32x4*)&sB[(wn * 64 + i * 32 + mrow) * BKB + slot];
      }
    }
#pragma unroll
    for (int ks = 0; ks < 2; ++ks)
#pragma unroll
      for (int i = 0; i < 2; ++i)
#pragma unroll
        for (int j = 0; j < 2; ++j)
          acc[i][j] = __builtin_amdgcn_mfma_i32_32x32x32_i8(
              af[ks][i], bfr[ks][j], acc[i][j], 0, 0, 0);

    __syncthreads();
  }

  // Epilogue: y = acc * srow[row] * gamma[col]
  const int colb = bn * BN + wn * 64 + (lane & 31);
  const int rowb = bm * BM + wm * 64 + 4 * (lane >> 5);
#pragma unroll
  for (int j = 0; j < 2; ++j) {
    const float g = gamma[colb + j * 32];
#pragma unroll
    for (int i = 0; i < 2; ++i) {
#pragma unroll
      for (int r = 0; r < 16; ++r) {
        const int grow = rowb + i * 32 + (r & 3) + 8 * (r >> 2);
        C[(size_t)grow * D_OUT + (colb + j * 32)] =
            (float)acc[i][j][r] * srow[grow] * g;
      }
    }
  }
}

extern "C" void kernel_launch(void* const* d_in, const int* in_sizes, int n_in,
                              void* d_out, int out_size, void* d_ws, size_t ws_size,
                              hipStream_t stream) {
  const float* x     = (const float*)d_in[0];  // (2,4096,4096)
  const float* nw    = (const float*)d_in[1];  // (4096,)
  const float* wq    = (const float*)d_in[2];  // (4096,4096) {-1,0,1}
  const float* gamma = (const float*)d_in[3];  // (4096,)
  float* y = (float*)d_out;

  // Workspace: xq i8 (32 MB) | wb i8 (16 MB) | srow fp32 (32 KB)
  signed char* xq = (signed char*)d_ws;
  signed char* wb = xq + (size_t)MROWS * D_IN;
  float* srow = (float*)(wb + (size_t)D_OUT * D_IN);

  prep_kernel<<<MROWS + 4096, 256, 0, stream>>>(x, nw, xq, srow, wq, wb);

  gemm_kernel<<<dim3(D_OUT / BN, MROWS / BM), 256, 0, stream>>>(xq, wb, srow, gamma, y);
}